// Round 7
// baseline (96.542 us; speedup 1.0000x reference)
//
#include <hip/hip_runtime.h>

#define N_PTS 16384
#define M_CENT 2048
#define MAXS 64
#define G 16        // centroids per block
#define CPW 4       // centroids per wave
#define PCH 1024    // points per chunk
#define NITER 16    // 16 x 1024 = 16384

// 512 blocks; block = 16 centroids; 4 waves x 4 centroids each.
// Double-buffered LDS point chunks (x,y,z,p2), one barrier per iteration.
__global__ __launch_bounds__(256) void ball_query_kernel(
    const float* __restrict__ pcs,      // [B, N, 3]
    const float* __restrict__ cent,     // [B, M, 3]
    int* __restrict__ out)              // [B, M, 64] int32
{
#pragma clang fp contract(off)
    __shared__ float4 buf[2][PCH];      // 32 KB: staged points (x,y,z,|p|^2)
    __shared__ int slots[G][MAXS];      // 4 KB
    __shared__ int cntlds[G];
    __shared__ int wflag[2][4];         // parity-buffered per-wave done flags

    const int tid  = threadIdx.x;
    const int lane = tid & 63;
    const int wid  = tid >> 6;
    const int cg0  = blockIdx.x * G;    // first centroid of block
    const int b    = blockIdx.x >> 7;   // 128 blocks per batch (2048/16)

    // this wave's 4 centroids
    float cx[CPW], cy[CPW], cz[CPW], c2[CPW];
    int   cnt[CPW];
#pragma unroll
    for (int c = 0; c < CPW; ++c) {
        const float* cp = cent + (size_t)(cg0 + wid * CPW + c) * 3;
        cx[c] = cp[0]; cy[c] = cp[1]; cz[c] = cp[2];
        float t = cx[c] * cx[c]; t += cy[c] * cy[c]; t += cz[c] * cz[c];
        c2[c] = t;
        cnt[c] = 0;
    }
    const float r2 = 0.04f;

    const float4* pq = (const float4*)(pcs + (size_t)b * N_PTS * 3);

    // ---- stage chunk 0: thread t covers points 4t..4t+3 (3 coalesced float4) ----
    {
        const float4 a = pq[3 * tid], b2 = pq[3 * tid + 1], cc = pq[3 * tid + 2];
        float p2;
        p2 = a.x * a.x;  p2 += a.y * a.y;  p2 += a.z * a.z;
        buf[0][4 * tid + 0] = make_float4(a.x, a.y, a.z, p2);
        p2 = a.w * a.w;  p2 += b2.x * b2.x;  p2 += b2.y * b2.y;
        buf[0][4 * tid + 1] = make_float4(a.w, b2.x, b2.y, p2);
        p2 = b2.z * b2.z;  p2 += b2.w * b2.w;  p2 += cc.x * cc.x;
        buf[0][4 * tid + 2] = make_float4(b2.z, b2.w, cc.x, p2);
        p2 = cc.y * cc.y;  p2 += cc.z * cc.z;  p2 += cc.w * cc.w;
        buf[0][4 * tid + 3] = make_float4(cc.y, cc.z, cc.w, p2);
    }
    __syncthreads();

    int alldone = 0;
    for (int it = 0; it < NITER && !alldone; ++it) {
        const int cur = it & 1;

        // ---- issue next-chunk global loads EARLY (latency hides under compute) ----
        const bool have_next = (it + 1) < NITER;
        float4 a, b2, cc;
        if (have_next) {
            const size_t base = (size_t)3 * ((it + 1) * 256 + tid);
            a = pq[base]; b2 = pq[base + 1]; cc = pq[base + 2];
        }

        // ---- test staged chunk vs this wave's not-done centroids ----
        const bool mydone0 = (cnt[0] >= MAXS) & (cnt[1] >= MAXS) &
                             (cnt[2] >= MAXS) & (cnt[3] >= MAXS);
        if (!mydone0) {
#pragma unroll 2
            for (int s = 0; s < 16; ++s) {
                const float4 pt = buf[cur][s * 64 + lane];
                const int pidx = it * PCH + s * 64 + lane;
#pragma unroll
                for (int c = 0; c < CPW; ++c) {
                    if (cnt[c] < MAXS) {   // wave-uniform skip
                        float cr = cx[c] * pt.x;  cr += cy[c] * pt.y;  cr += cz[c] * pt.z;
                        const float d2 = (c2[c] + pt.w) - 2.0f * cr;
                        const bool hit = d2 <= r2;
                        const unsigned long long m = __ballot(hit);
                        if (hit) {
                            const int rk = cnt[c] + (int)__popcll(m & ((1ull << lane) - 1ull));
                            if (rk < MAXS) slots[wid * CPW + c][rk] = pidx;
                        }
                        cnt[c] += (int)__popcll(m);
                    }
                }
            }
        }

        // ---- write next chunk into the other buffer (loads already in flight) ----
        if (have_next) {
            float4* dst = buf[cur ^ 1];
            float p2;
            p2 = a.x * a.x;  p2 += a.y * a.y;  p2 += a.z * a.z;
            dst[4 * tid + 0] = make_float4(a.x, a.y, a.z, p2);
            p2 = a.w * a.w;  p2 += b2.x * b2.x;  p2 += b2.y * b2.y;
            dst[4 * tid + 1] = make_float4(a.w, b2.x, b2.y, p2);
            p2 = b2.z * b2.z;  p2 += b2.w * b2.w;  p2 += cc.x * cc.x;
            dst[4 * tid + 2] = make_float4(b2.z, b2.w, cc.x, p2);
            p2 = cc.y * cc.y;  p2 += cc.z * cc.z;  p2 += cc.w * cc.w;
            dst[4 * tid + 3] = make_float4(cc.y, cc.z, cc.w, p2);
        }

        // ---- block-uniform exit decision (parity flags, single barrier) ----
        const bool md = (cnt[0] >= MAXS) && (cnt[1] >= MAXS) &&
                        (cnt[2] >= MAXS) && (cnt[3] >= MAXS);
        if (lane == 0) wflag[cur][wid] = md ? 1 : 0;
        __syncthreads();
        alldone = wflag[cur][0] & wflag[cur][1] & wflag[cur][2] & wflag[cur][3];
    }

    // ---- publish counts, then write output ----
    if (lane == 0) {
        cntlds[wid * CPW + 0] = cnt[0];
        cntlds[wid * CPW + 1] = cnt[1];
        cntlds[wid * CPW + 2] = cnt[2];
        cntlds[wid * CPW + 3] = cnt[3];
    }
    __syncthreads();

    // thread t writes 4 consecutive outputs of centroid c = t>>4
    const int c  = tid >> 4;
    const int s0 = (tid & 15) * 4;
    const int k  = cntlds[c] < MAXS ? cntlds[c] : MAXS;
    const int4 v = *(const int4*)&slots[c][s0];
    const int fallback = (k == 0) ? N_PTS : slots[c][0];
    int4 o;
    o.x = (s0 + 0 < k) ? v.x : fallback;
    o.y = (s0 + 1 < k) ? v.y : fallback;
    o.z = (s0 + 2 < k) ? v.z : fallback;
    o.w = (s0 + 3 < k) ? v.w : fallback;
    *(int4*)(out + ((size_t)cg0 << 6) + 4 * tid) = o;
}

extern "C" void kernel_launch(void* const* d_in, const int* in_sizes, int n_in,
                              void* d_out, int out_size, void* d_ws, size_t ws_size,
                              hipStream_t stream) {
    const float* pcs  = (const float*)d_in[0];
    const float* cent = (const float*)d_in[1];
    int* out = (int*)d_out;

    const int B = in_sizes[0] / (N_PTS * 3);     // 4
    const int grid = B * M_CENT / G;             // 512 blocks, 16 centroids each

    ball_query_kernel<<<grid, 256, 0, stream>>>(pcs, cent, out);
}

// Round 8
// 76.642 us; speedup vs baseline: 1.2596x; 1.2596x over previous
//
#include <hip/hip_runtime.h>

#define N_PTS 16384
#define M_CENT 2048
#define MAXS 64
#define NWAVE 4
#define NITER 16   // 16 x 1024 points = 16384

// One block = one centroid. 4 waves x 64 lanes x 4 points = 1024 points/iter.
// 8192 blocks -> 4 residency rounds => backfill; straggler chain capped at 16 iters.
__global__ __launch_bounds__(256) void ball_query_kernel(
    const float* __restrict__ pcs,      // [B, N, 3]
    const float* __restrict__ cent,     // [B, M, 3]
    int* __restrict__ out)              // [B, M, 64] int32 indices
{
#pragma clang fp contract(off)
    __shared__ int slots[MAXS];
    __shared__ int wavecnt[2][NWAVE];   // parity double-buffer: 1 barrier/iter

    const int tid  = threadIdx.x;
    const int lane = tid & 63;
    const int wid  = tid >> 6;
    const int cg   = blockIdx.x;        // centroid id in [0, B*M)
    const int b    = cg >> 11;          // / M_CENT

    const float* cp = cent + (size_t)cg * 3;
    const float cx = cp[0], cy = cp[1], cz = cp[2];
    float c2 = cx * cx;
    c2 += cy * cy;
    c2 += cz * cz;
    const float r2 = 0.04f;

    const float4* pq = (const float4*)(pcs + (size_t)b * N_PTS * 3);
    const unsigned long long pre = (1ull << lane) - 1ull;

    // thread t covers points 4t..4t+3 of each 1024-chunk: 3 coalesced float4
    int qi = 3 * tid;                   // float4 index; += 768 per iter
    float4 a = pq[qi], e = pq[qi + 1], f = pq[qi + 2];

    int count = 0;                      // block-uniform running hit count
    int it = 0;
    while (true) {
        // ---- issue next chunk's loads FIRST (hide L2 latency under compute) ----
        const bool have_next = (it + 1) < NITER;
        float4 na, ne, nf;
        if (have_next) {
            const int nq = qi + 768;
            na = pq[nq]; ne = pq[nq + 1]; nf = pq[nq + 2];
        }

        // ---- 4 point tests per lane ----
        // P0=(a.x,a.y,a.z) P1=(a.w,e.x,e.y) P2=(e.z,e.w,f.x) P3=(f.y,f.z,f.w)
        float p2, cr, d2;
        p2 = a.x * a.x;  p2 += a.y * a.y;  p2 += a.z * a.z;
        cr = cx * a.x;   cr += cy * a.y;   cr += cz * a.z;
        d2 = (c2 + p2) - 2.0f * cr;
        const bool h0 = d2 <= r2;

        p2 = a.w * a.w;  p2 += e.x * e.x;  p2 += e.y * e.y;
        cr = cx * a.w;   cr += cy * e.x;   cr += cz * e.y;
        d2 = (c2 + p2) - 2.0f * cr;
        const bool h1 = d2 <= r2;

        p2 = e.z * e.z;  p2 += e.w * e.w;  p2 += f.x * f.x;
        cr = cx * e.z;   cr += cy * e.w;   cr += cz * f.x;
        d2 = (c2 + p2) - 2.0f * cr;
        const bool h2 = d2 <= r2;

        p2 = f.y * f.y;  p2 += f.z * f.z;  p2 += f.w * f.w;
        cr = cx * f.y;   cr += cy * f.z;   cr += cz * f.w;
        d2 = (c2 + p2) - 2.0f * cr;
        const bool h3 = d2 <= r2;

        const unsigned long long m0 = __ballot(h0);
        const unsigned long long m1 = __ballot(h1);
        const unsigned long long m2 = __ballot(h2);
        const unsigned long long m3 = __ballot(h3);

        const int mycnt = (int)__popcll(m0) + (int)__popcll(m1)
                        + (int)__popcll(m2) + (int)__popcll(m3);
        const int par = it & 1;
        if (lane == 0) wavecnt[par][wid] = mycnt;
        __syncthreads();

        // branchless cross-wave exclusive prefix + total (broadcast LDS reads)
        const int c0 = wavecnt[par][0];
        const int c1 = wavecnt[par][1];
        const int cw = wavecnt[par][2];
        const int c3 = wavecnt[par][3];
        const int tot = c0 + c1 + cw + c3;
        int prew = (wid > 0) ? c0 : 0;
        prew += (wid > 1) ? c1 : 0;
        prew += (wid > 2) ? cw : 0;

        // ranks (ascending point-index order within block)
        const int below = (int)__popcll(m0 & pre) + (int)__popcll(m1 & pre)
                        + (int)__popcll(m2 & pre) + (int)__popcll(m3 & pre);
        const int r0 = count + prew + below;
        const int r1 = r0  + (int)((m0 >> lane) & 1ull);
        const int r2i = r1 + (int)((m1 >> lane) & 1ull);
        const int r3 = r2i + (int)((m2 >> lane) & 1ull);

        const int pidx = (it << 10) + (tid << 2);
        if (h0 && r0  < MAXS) slots[r0]  = pidx;
        if (h1 && r1  < MAXS) slots[r1]  = pidx + 1;
        if (h2 && r2i < MAXS) slots[r2i] = pidx + 2;
        if (h3 && r3  < MAXS) slots[r3]  = pidx + 3;

        count += tot;                    // block-uniform
        ++it;
        if (count >= MAXS || it >= NITER) break;   // uniform exit: barriers matched
        qi += 768; a = na; e = ne; f = nf;
    }

    __syncthreads();                     // slots visible; reached uniformly

    if (wid == 0) {
        const int cnt = count < MAXS ? count : MAXS;
        int val;
        if (cnt == 0) {
            val = N_PTS;                 // no hits: reference pads with N
        } else {
            val = (lane < cnt) ? slots[lane] : slots[0];
        }
        out[((size_t)cg << 6) + lane] = val;
    }
}

extern "C" void kernel_launch(void* const* d_in, const int* in_sizes, int n_in,
                              void* d_out, int out_size, void* d_ws, size_t ws_size,
                              hipStream_t stream) {
    const float* pcs  = (const float*)d_in[0];
    const float* cent = (const float*)d_in[1];
    int* out = (int*)d_out;

    const int B = in_sizes[0] / (N_PTS * 3);     // 4
    const int grid = B * M_CENT;                 // 8192 blocks, 1 centroid each

    ball_query_kernel<<<grid, 256, 0, stream>>>(pcs, cent, out);
}